// Round 6
// baseline (247.126 us; speedup 1.0000x reference)
//
#include <hip/hip_runtime.h>

#define N_NODES 4096
#define FIN     512
#define FOUT    256
#define NSPLIT  4
#define NTILES  ((N_NODES / NSPLIT) / 64)   // 16
#define ITILE   128                         // i-rows per attn block

typedef __attribute__((ext_vector_type(8))) short bf16x8s;
typedef __attribute__((ext_vector_type(4))) float f32x4;
typedef __attribute__((ext_vector_type(8))) unsigned short u16x8;
typedef unsigned short u16;
typedef unsigned int   u32;

__device__ inline u16 f2b(float f) {
    union { float f; unsigned int u; } v; v.f = f;
    unsigned int r = v.u + 0x7fffu + ((v.u >> 16) & 1u);   // RTNE
    return (u16)(r >> 16);
}

// ---------------------------------------------------------------------------
// prep: [0,1024)    h fp32 -> hb bf16
//       [1024,1088) W_b -> WTb bf16 transposed [n][k]
//       [1088]      zero s1/s2
// ---------------------------------------------------------------------------
__global__ __launch_bounds__(256) void prep_kernel(
    const float* __restrict__ h, const float* __restrict__ Wn,
    const float* __restrict__ Wd,
    u16* __restrict__ hb, u16* __restrict__ WTb, float* __restrict__ s12)
{
    __shared__ u16 tl[64 * 72];
    const int t = threadIdx.x;
    const int bid = blockIdx.x;

    if (bid < 1024) {                       // h convert
        int idx = (bid * 256 + t) * 8;
        float4 f0 = *(const float4*)&h[idx];
        float4 f1 = *(const float4*)&h[idx + 4];
        u16x8 o;
        o[0]=f2b(f0.x); o[1]=f2b(f0.y); o[2]=f2b(f0.z); o[3]=f2b(f0.w);
        o[4]=f2b(f1.x); o[5]=f2b(f1.y); o[6]=f2b(f1.z); o[7]=f2b(f1.w);
        *(u16x8*)&hb[idx] = o;
    } else if (bid < 1088) {                // W transpose+convert, 64x64 tiles
        int id = bid - 1024;
        int kx = id & 7, ny = (id >> 3) & 3, b = id >> 5;
        const float* W = b ? Wd : Wn;
        int k0 = kx * 64, n0 = ny * 64;
        int kr = t >> 2, nc0 = (t & 3) * 16;
        const float* src = W + (size_t)(k0 + kr) * FOUT + n0 + nc0;
        #pragma unroll
        for (int jv = 0; jv < 4; ++jv) {
            float4 f = *(const float4*)(src + jv * 4);
            tl[(nc0 + jv * 4 + 0) * 72 + kr] = f2b(f.x);
            tl[(nc0 + jv * 4 + 1) * 72 + kr] = f2b(f.y);
            tl[(nc0 + jv * 4 + 2) * 72 + kr] = f2b(f.z);
            tl[(nc0 + jv * 4 + 3) * 72 + kr] = f2b(f.w);
        }
        __syncthreads();
        int n = t >> 2, kc0 = (t & 3) * 16;
        u16* dst = WTb + ((size_t)b << 17) + (size_t)(n0 + n) * FIN + k0 + kc0;
        *(uint4*)dst       = *(uint4*)&tl[n * 72 + kc0];
        *(uint4*)(dst + 8) = *(uint4*)&tl[n * 72 + kc0 + 8];
    } else {                                // zero s1,s2 (16384 floats)
        float4 z = {0.f, 0.f, 0.f, 0.f};
        float4* p4 = (float4*)s12;
        #pragma unroll
        for (int k = 0; k < 16; ++k) p4[k * 256 + t] = z;
    }
}

// ---------------------------------------------------------------------------
// wh_gemm: DE-STAGED K-loop — hb (4 MB) and WTb (0.5 MB) are L2/L3-resident,
// so MFMA fragments are loaded straight from global into registers; no LDS,
// no barriers in the K-loop. Epilogue (s1/s2 + transposed WhT write) as
// before. grid (64, 4, 2) x 256.
// ---------------------------------------------------------------------------
__global__ __launch_bounds__(256) void wh_gemm_kernel(
    const u16* __restrict__ hb, const u16* __restrict__ WTb,
    const float* __restrict__ a1n, const float* __restrict__ a2n,
    const float* __restrict__ a1d, const float* __restrict__ a2d,
    u16* __restrict__ WhT, float* __restrict__ s1, float* __restrict__ s2)
{
    __shared__ u16 smem[64 * 72];

    const int t = threadIdx.x, lane = t & 63, w = t >> 6;
    const int q = lane >> 4, ln = lane & 15;
    const int i0 = blockIdx.x * 64, n0 = blockIdx.y * 64, b = blockIdx.z;
    const u16* wt = WTb + ((size_t)b << 17);

    const u16* arow = hb + (size_t)(i0 + w * 16 + ln) * FIN;
    const u16* brow0 = wt + (size_t)(n0 + 0 * 16 + ln) * FIN;
    const u16* brow1 = wt + (size_t)(n0 + 1 * 16 + ln) * FIN;
    const u16* brow2 = wt + (size_t)(n0 + 2 * 16 + ln) * FIN;
    const u16* brow3 = wt + (size_t)(n0 + 3 * 16 + ln) * FIN;

    f32x4 acc[4];
    #pragma unroll
    for (int i = 0; i < 4; ++i) acc[i] = (f32x4){0.f, 0.f, 0.f, 0.f};

    #pragma unroll
    for (int kt = 0; kt < 8; ++kt) {
        #pragma unroll
        for (int ks = 0; ks < 2; ++ks) {
            const int ko = kt * 64 + (ks * 4 + q) * 8;
            bf16x8s af = *(const bf16x8s*)&arow[ko];
            bf16x8s b0 = *(const bf16x8s*)&brow0[ko];
            bf16x8s b1 = *(const bf16x8s*)&brow1[ko];
            bf16x8s b2 = *(const bf16x8s*)&brow2[ko];
            bf16x8s b3 = *(const bf16x8s*)&brow3[ko];
            acc[0] = __builtin_amdgcn_mfma_f32_16x16x32_bf16(af, b0, acc[0], 0, 0, 0);
            acc[1] = __builtin_amdgcn_mfma_f32_16x16x32_bf16(af, b1, acc[1], 0, 0, 0);
            acc[2] = __builtin_amdgcn_mfma_f32_16x16x32_bf16(af, b2, acc[2], 0, 0, 0);
            acc[3] = __builtin_amdgcn_mfma_f32_16x16x32_bf16(af, b3, acc[3], 0, 0, 0);
        }
    }

    {
        const float* a1 = b ? a1d : a1n;
        const float* a2 = b ? a2d : a2n;
        float s1p[4] = {0.f, 0.f, 0.f, 0.f};
        float s2p[4] = {0.f, 0.f, 0.f, 0.f};
        #pragma unroll
        for (int nt = 0; nt < 4; ++nt) {
            float va1 = a1[n0 + nt * 16 + ln];
            float va2 = a2[n0 + nt * 16 + ln];
            #pragma unroll
            for (int r = 0; r < 4; ++r) {
                s1p[r] += acc[nt][r] * va1;
                s2p[r] += acc[nt][r] * va2;
            }
        }
        #pragma unroll
        for (int r = 0; r < 4; ++r) {
            #pragma unroll
            for (int off = 8; off >= 1; off >>= 1) {
                s1p[r] += __shfl_xor(s1p[r], off);
                s2p[r] += __shfl_xor(s2p[r], off);
            }
            if (ln == 0) {
                int row = i0 + w * 16 + q * 4 + r;
                atomicAdd(&s1[b * N_NODES + row], s1p[r]);
                atomicAdd(&s2[b * N_NODES + row], s2p[r]);
            }
        }
    }

    __syncthreads();
    #pragma unroll
    for (int nt = 0; nt < 4; ++nt)
        #pragma unroll
        for (int r = 0; r < 4; ++r)
            smem[(nt * 16 + ln) * 72 + (w * 16 + q * 4 + r)] = f2b(acc[nt][r]);
    __syncthreads();
    {
        const int nl = t >> 2, is = (t & 3) * 16;
        u16* dst = WhT + ((size_t)b << 20) + (size_t)(n0 + nl) * N_NODES + i0 + is;
        *(uint4*)dst       = *(uint4*)&smem[nl * 72 + is];
        *(uint4*)(dst + 8) = *(uint4*)&smem[nl * 72 + is + 8];
    }
}

// ---------------------------------------------------------------------------
// attn: 128 rows x 1024-j per 1024-thread block; DE-STAGED B operand.
// WhT (4 MB, L2-resident) fragments are loaded directly from global per
// MFMA — no wht_lds, no global_load_lds, no vmcnt drain. Only P goes
// through LDS (2 x 16 KB ping-pong) with ONE barrier per tile (a wave
// can't get 2 tiles ahead, so ping-pong is race-free).
// grid (32, NSPLIT, 2). Wave w: ih=w>>2 (32 rows), nq=w&3 (64 cols).
// ---------------------------------------------------------------------------
__global__ __launch_bounds__(1024) void attn_kernel(
    const int* __restrict__ adj_n, const int* __restrict__ adj_d,
    const u16* __restrict__ WhT,
    const float* __restrict__ s1, const float* __restrict__ s2,
    float* __restrict__ num_ws, float* __restrict__ den_ws)
{
    __shared__ u16 p_lds[2][128 * 64];  // 2 x 16 KB, swizzled, ping-pong

    const int t = threadIdx.x, lane = t & 63, w = t >> 6;   // w 0..15
    const int q = lane >> 4, ln = lane & 15;
    const int ih = w >> 2;              // i-quarter (32 rows)
    const int nq = w & 3;               // n-quarter (64 cols)
    const int b = blockIdx.z, split = blockIdx.y;
    const int i0 = blockIdx.x * ITILE;

    const int* adjb = b ? adj_d : adj_n;
    const u16* whtB = WhT + ((size_t)b << 20);
    const float* s1b = s1 + b * N_NODES;
    const float* s2b = s2 + b * N_NODES;

    // per-lane B-row pointers (4 nt rows of this wave's n-quarter)
    const u16* brow0 = whtB + (size_t)(nq * 64 + 0 * 16 + ln) * N_NODES;
    const u16* brow1 = whtB + (size_t)(nq * 64 + 1 * 16 + ln) * N_NODES;
    const u16* brow2 = whtB + (size_t)(nq * 64 + 2 * 16 + ln) * N_NODES;
    const u16* brow3 = whtB + (size_t)(nq * 64 + 3 * 16 + ln) * N_NODES;

    const int pr = t >> 3;              // P row 0..127 (one row per thread)
    const int cw = t & 7;               // P k-chunk 0..7
    const int pc = cw * 8;
    const float s1v = s1b[i0 + pr];
    const size_t arow = (size_t)(i0 + pr) * N_NODES + pc;
    const int swp = (cw ^ (pr & 7)) * 8;

    float den0 = 0.f;                   // full sum lives on (t&7)==0 threads

    f32x4 acc[2][4];
    #pragma unroll
    for (int mt = 0; mt < 2; ++mt)
        #pragma unroll
        for (int nt = 0; nt < 4; ++nt) acc[mt][nt] = (f32x4){0.f, 0.f, 0.f, 0.f};

    const int jbase = split * (N_NODES / NSPLIT);

    int4 a0_pf = *(const int4*)&adjb[arow + jbase];
    int4 a1_pf = *(const int4*)&adjb[arow + jbase + 4];
    float4 sv0_pf = *(const float4*)&s2b[jbase + pc];
    float4 sv1_pf = *(const float4*)&s2b[jbase + pc + 4];

    for (int jt = 0; jt < NTILES; ++jt) {
        const int j0 = jbase + jt * 64;
        const int cur = jt & 1;

        int4 a0 = a0_pf, a1 = a1_pf;
        float4 sv0 = sv0_pf, sv1 = sv1_pf;
        if (jt < NTILES - 1) {             // prefetch next tile's adj/s2
            const int jn = j0 + 64;
            a0_pf = *(const int4*)&adjb[arow + jn];
            a1_pf = *(const int4*)&adjb[arow + jn + 4];
            sv0_pf = *(const float4*)&s2b[jn + pc];
            sv1_pf = *(const float4*)&s2b[jn + pc + 4];
        }
        int v[8] = {a0.x, a0.y, a0.z, a0.w, a1.x, a1.y, a1.z, a1.w};
        float svf[8] = {sv0.x, sv0.y, sv0.z, sv0.w, sv1.x, sv1.y, sv1.z, sv1.w};
        float d = 0.f;
        u16x8 pk;
        #pragma unroll
        for (int jj = 0; jj < 8; ++jj) {
            float x = s1v + svf[jj];
            float p = (v[jj] > 0) ? __expf(fmaxf(x, 0.2f * x)) : 0.f;
            d += p;
            pk[jj] = f2b(p);
        }
        d += __shfl_down(d, 4, 8);
        d += __shfl_down(d, 2, 8);
        d += __shfl_down(d, 1, 8);
        if ((t & 7) == 0) den0 += d;
        *(u16x8*)&p_lds[cur][pr * 64 + swp] = pk;
        __syncthreads();                // p_lds[cur] committed
        #pragma unroll
        for (int ks = 0; ks < 2; ++ks) {
            const int sw = ((ks * 4 + q) ^ (ln & 7)) * 8;
            const int ko = j0 + (ks * 4 + q) * 8;
            bf16x8s af0 = *(const bf16x8s*)&p_lds[cur][(ih * 32 + 0 * 16 + ln) * 64 + sw];
            bf16x8s af1 = *(const bf16x8s*)&p_lds[cur][(ih * 32 + 1 * 16 + ln) * 64 + sw];
            bf16x8s b0 = *(const bf16x8s*)&brow0[ko];
            bf16x8s b1 = *(const bf16x8s*)&brow1[ko];
            bf16x8s b2 = *(const bf16x8s*)&brow2[ko];
            bf16x8s b3 = *(const bf16x8s*)&brow3[ko];
            acc[0][0] = __builtin_amdgcn_mfma_f32_16x16x32_bf16(af0, b0, acc[0][0], 0, 0, 0);
            acc[1][0] = __builtin_amdgcn_mfma_f32_16x16x32_bf16(af1, b0, acc[1][0], 0, 0, 0);
            acc[0][1] = __builtin_amdgcn_mfma_f32_16x16x32_bf16(af0, b1, acc[0][1], 0, 0, 0);
            acc[1][1] = __builtin_amdgcn_mfma_f32_16x16x32_bf16(af1, b1, acc[1][1], 0, 0, 0);
            acc[0][2] = __builtin_amdgcn_mfma_f32_16x16x32_bf16(af0, b2, acc[0][2], 0, 0, 0);
            acc[1][2] = __builtin_amdgcn_mfma_f32_16x16x32_bf16(af1, b2, acc[1][2], 0, 0, 0);
            acc[0][3] = __builtin_amdgcn_mfma_f32_16x16x32_bf16(af0, b3, acc[0][3], 0, 0, 0);
            acc[1][3] = __builtin_amdgcn_mfma_f32_16x16x32_bf16(af1, b3, acc[1][3], 0, 0, 0);
        }
        // no second barrier: next iteration writes p_lds[cur^1]; a wave
        // cannot pass the NEXT barrier until all waves left this MFMA.
    }
    const size_t pbase = (size_t)(b * NSPLIT + split) * N_NODES;
    #pragma unroll
    for (int mt = 0; mt < 2; ++mt)
        #pragma unroll
        for (int r = 0; r < 4; ++r) {
            int row = ih * 32 + mt * 16 + q * 4 + r;
            #pragma unroll
            for (int nt = 0; nt < 4; ++nt)
                num_ws[(pbase + i0 + row) * FOUT + nq * 64 + nt * 16 + ln] = acc[mt][nt][r];
        }
    if ((t & 7) == 0) den_ws[pbase + i0 + pr] = den0;
}

// ---------------------------------------------------------------------------
// reduce: sum splits, elu(num/den), merge branches.
// ---------------------------------------------------------------------------
__global__ __launch_bounds__(256) void reduce_kernel(
    const float* __restrict__ num_ws, const float* __restrict__ den_ws,
    float* __restrict__ out)
{
    int gid = blockIdx.x * 256 + threadIdx.x;
    int i = gid >> 6;
    int f4 = (gid & 63) * 4;
    float4 o = {0.f, 0.f, 0.f, 0.f};
    #pragma unroll
    for (int b = 0; b < 2; ++b) {
        float4 num = {0.f, 0.f, 0.f, 0.f};
        float den = 0.f;
        #pragma unroll
        for (int s = 0; s < NSPLIT; ++s) {
            const float4 v = *(const float4*)&num_ws[((size_t)(b * NSPLIT + s) * N_NODES + i) * FOUT + f4];
            num.x += v.x; num.y += v.y; num.z += v.z; num.w += v.w;
            den += den_ws[(size_t)(b * NSPLIT + s) * N_NODES + i];
        }
        float inv = 1.0f / den;
        float e0 = num.x * inv, e1 = num.y * inv, e2 = num.z * inv, e3 = num.w * inv;
        o.x += (e0 > 0.f) ? e0 : expm1f(e0);
        o.y += (e1 > 0.f) ? e1 : expm1f(e1);
        o.z += (e2 > 0.f) ? e2 : expm1f(e2);
        o.w += (e3 > 0.f) ? e3 : expm1f(e3);
    }
    *(float4*)&out[(size_t)i * FOUT + f4] = o;
}

extern "C" void kernel_launch(void* const* d_in, const int* in_sizes, int n_in,
                              void* d_out, int out_size, void* d_ws, size_t ws_size,
                              hipStream_t stream) {
    const float* h    = (const float*)d_in[0];
    const int*   adjn = (const int*)d_in[1];
    const int*   adjd = (const int*)d_in[2];
    const float* Wn   = (const float*)d_in[4];
    const float* a1n  = (const float*)d_in[5];
    const float* a2n  = (const float*)d_in[6];
    const float* Wd   = (const float*)d_in[7];
    const float* a1d  = (const float*)d_in[8];
    const float* a2d  = (const float*)d_in[9];

    char* ws = (char*)d_ws;
    // [0,4M): WhT   [4M,8M): (free)   [8M,8M+192K): s1,s2,den
    // [8.25M,12.25M): hb   [12.25M,12.75M): WTb   (dead after wh_gemm)
    // [8.25M,40.25M): num  (overlays hb/WTb; written by attn after wh_gemm)
    u16*  WhT  = (u16*)ws;
    float* s1  = (float*)(ws + ((size_t)8 << 20));
    float* s2  = s1 + 2 * N_NODES;
    float* den = s2 + 2 * N_NODES;
    u16*  hb   = (u16*)(ws + ((size_t)8 << 20) + ((size_t)256 << 10));
    u16*  WTb  = (u16*)(ws + ((size_t)12 << 20) + ((size_t)256 << 10));
    float* num = (float*)(ws + ((size_t)8 << 20) + ((size_t)256 << 10));

    prep_kernel<<<1089, 256, 0, stream>>>(h, Wn, Wd, hb, WTb, s1);
    wh_gemm_kernel<<<dim3(64, 4, 2), 256, 0, stream>>>(hb, WTb, a1n, a2n, a1d, a2d, WhT, s1, s2);
    attn_kernel<<<dim3(N_NODES / ITILE, NSPLIT, 2), 1024, 0, stream>>>(adjn, adjd, WhT, s1, s2, num, den);
    reduce_kernel<<<1024, 256, 0, stream>>>(num, den, (float*)d_out);
}

// Round 7
// 214.178 us; speedup vs baseline: 1.1538x; 1.1538x over previous
//
#include <hip/hip_runtime.h>
#include <hip/hip_bf16.h>

#define N_NODES 4096
#define FIN     512
#define FOUT    256
#define NSPLIT  4
#define JTILE   128
#define NTILES  ((N_NODES / NSPLIT) / JTILE)  // 8
#define ITILE   128                           // i-rows per attn block

typedef __attribute__((ext_vector_type(8))) short bf16x8s;
typedef __attribute__((ext_vector_type(4))) float f32x4;
typedef __attribute__((ext_vector_type(8))) unsigned short u16x8;
typedef unsigned short u16;
typedef unsigned int   u32;

__device__ inline u16 f2b(float f) {
    union { float f; unsigned int u; } v; v.f = f;
    unsigned int r = v.u + 0x7fffu + ((v.u >> 16) & 1u);   // RTNE
    return (u16)(r >> 16);
}

__device__ inline u16 f2b_fast(float f) {                  // RTNE via HW cvt
    return __bfloat16_as_ushort(__float2bfloat16(f));
}

// ---------------------------------------------------------------------------
// prep: [0,1024)    h fp32 -> hb bf16
//       [1024,1088) W_b -> WTb bf16 transposed [n][k]
//       [1088]      zero s1/s2
// ---------------------------------------------------------------------------
__global__ __launch_bounds__(256) void prep_kernel(
    const float* __restrict__ h, const float* __restrict__ Wn,
    const float* __restrict__ Wd,
    u16* __restrict__ hb, u16* __restrict__ WTb, float* __restrict__ s12)
{
    __shared__ u16 tl[64 * 72];
    const int t = threadIdx.x;
    const int bid = blockIdx.x;

    if (bid < 1024) {                       // h convert
        int idx = (bid * 256 + t) * 8;
        float4 f0 = *(const float4*)&h[idx];
        float4 f1 = *(const float4*)&h[idx + 4];
        u16x8 o;
        o[0]=f2b(f0.x); o[1]=f2b(f0.y); o[2]=f2b(f0.z); o[3]=f2b(f0.w);
        o[4]=f2b(f1.x); o[5]=f2b(f1.y); o[6]=f2b(f1.z); o[7]=f2b(f1.w);
        *(u16x8*)&hb[idx] = o;
    } else if (bid < 1088) {                // W transpose+convert, 64x64 tiles
        int id = bid - 1024;
        int kx = id & 7, ny = (id >> 3) & 3, b = id >> 5;
        const float* W = b ? Wd : Wn;
        int k0 = kx * 64, n0 = ny * 64;
        int kr = t >> 2, nc0 = (t & 3) * 16;
        const float* src = W + (size_t)(k0 + kr) * FOUT + n0 + nc0;
        #pragma unroll
        for (int jv = 0; jv < 4; ++jv) {
            float4 f = *(const float4*)(src + jv * 4);
            tl[(nc0 + jv * 4 + 0) * 72 + kr] = f2b(f.x);
            tl[(nc0 + jv * 4 + 1) * 72 + kr] = f2b(f.y);
            tl[(nc0 + jv * 4 + 2) * 72 + kr] = f2b(f.z);
            tl[(nc0 + jv * 4 + 3) * 72 + kr] = f2b(f.w);
        }
        __syncthreads();
        int n = t >> 2, kc0 = (t & 3) * 16;
        u16* dst = WTb + ((size_t)b << 17) + (size_t)(n0 + n) * FIN + k0 + kc0;
        *(uint4*)dst       = *(uint4*)&tl[n * 72 + kc0];
        *(uint4*)(dst + 8) = *(uint4*)&tl[n * 72 + kc0 + 8];
    } else {                                // zero s1,s2 (16384 floats)
        float4 z = {0.f, 0.f, 0.f, 0.f};
        float4* p4 = (float4*)s12;
        #pragma unroll
        for (int k = 0; k < 16; ++k) p4[k * 256 + t] = z;
    }
}

// ---------------------------------------------------------------------------
// wh_gemm (staged R5 version): WhT[b][n][i] = (hb @ W_b)[i][n]; epilogue
// accumulates s1/s2. grid (64, 4, 2).
// ---------------------------------------------------------------------------
__global__ __launch_bounds__(256) void wh_gemm_kernel(
    const u16* __restrict__ hb, const u16* __restrict__ WTb,
    const float* __restrict__ a1n, const float* __restrict__ a2n,
    const float* __restrict__ a1d, const float* __restrict__ a2d,
    u16* __restrict__ WhT, float* __restrict__ s1, float* __restrict__ s2)
{
    __shared__ u16 smem[8192];
    u16* a_lds = smem;
    u16* b_lds = smem + 4096;

    const int t = threadIdx.x, lane = t & 63, w = t >> 6;
    const int q = lane >> 4, ln = lane & 15;
    const int i0 = blockIdx.x * 64, n0 = blockIdx.y * 64, b = blockIdx.z;
    const u16* wt = WTb + ((size_t)b << 17);

    f32x4 acc[4];
    #pragma unroll
    for (int i = 0; i < 4; ++i) acc[i] = (f32x4){0.f, 0.f, 0.f, 0.f};

    for (int kt = 0; kt < 8; ++kt) {
        const int k0 = kt * 64;
        __syncthreads();
        #pragma unroll
        for (int it = 0; it < 2; ++it) {
            int chunk = it * 256 + t;
            int r = chunk >> 3, kc = chunk & 7;
            const u16* g = hb + (size_t)(i0 + r) * FIN + k0 + ((kc ^ (r & 7)) * 8);
            u16* l = a_lds + (it * 256 + w * 64) * 8;
            __builtin_amdgcn_global_load_lds(
                (const __attribute__((address_space(1))) void*)g,
                (__attribute__((address_space(3))) void*)l, 16, 0, 0);
        }
        #pragma unroll
        for (int it = 0; it < 2; ++it) {
            int chunk = it * 256 + t;
            int n = chunk >> 3, kc = chunk & 7;
            const u16* g = wt + (size_t)(n0 + n) * FIN + k0 + ((kc ^ (n & 7)) * 8);
            u16* l = b_lds + (it * 256 + w * 64) * 8;
            __builtin_amdgcn_global_load_lds(
                (const __attribute__((address_space(1))) void*)g,
                (__attribute__((address_space(3))) void*)l, 16, 0, 0);
        }
        __syncthreads();
        #pragma unroll
        for (int ks = 0; ks < 2; ++ks) {
            int sw = ((ks * 4 + q) ^ (ln & 7)) * 8;
            bf16x8s af = *(const bf16x8s*)&a_lds[(w * 16 + ln) * 64 + sw];
            #pragma unroll
            for (int nt = 0; nt < 4; ++nt) {
                bf16x8s bfv = *(const bf16x8s*)&b_lds[(nt * 16 + ln) * 64 + sw];
                acc[nt] = __builtin_amdgcn_mfma_f32_16x16x32_bf16(af, bfv, acc[nt], 0, 0, 0);
            }
        }
    }

    {
        const float* a1 = b ? a1d : a1n;
        const float* a2 = b ? a2d : a2n;
        float s1p[4] = {0.f, 0.f, 0.f, 0.f};
        float s2p[4] = {0.f, 0.f, 0.f, 0.f};
        #pragma unroll
        for (int nt = 0; nt < 4; ++nt) {
            float va1 = a1[n0 + nt * 16 + ln];
            float va2 = a2[n0 + nt * 16 + ln];
            #pragma unroll
            for (int r = 0; r < 4; ++r) {
                s1p[r] += acc[nt][r] * va1;
                s2p[r] += acc[nt][r] * va2;
            }
        }
        #pragma unroll
        for (int r = 0; r < 4; ++r) {
            #pragma unroll
            for (int off = 8; off >= 1; off >>= 1) {
                s1p[r] += __shfl_xor(s1p[r], off);
                s2p[r] += __shfl_xor(s2p[r], off);
            }
            if (ln == 0) {
                int row = i0 + w * 16 + q * 4 + r;
                atomicAdd(&s1[b * N_NODES + row], s1p[r]);
                atomicAdd(&s2[b * N_NODES + row], s2p[r]);
            }
        }
    }

    __syncthreads();
    #pragma unroll
    for (int nt = 0; nt < 4; ++nt)
        #pragma unroll
        for (int r = 0; r < 4; ++r)
            smem[(nt * 16 + ln) * 72 + (w * 16 + q * 4 + r)] = f2b(acc[nt][r]);
    __syncthreads();
    {
        const int nl = t >> 2, is = (t & 3) * 16;
        u16* dst = WhT + ((size_t)b << 20) + (size_t)(n0 + nl) * N_NODES + i0 + is;
        *(uint4*)dst       = *(uint4*)&smem[nl * 72 + is];
        *(uint4*)(dst + 8) = *(uint4*)&smem[nl * 72 + is + 8];
    }
}

// ---------------------------------------------------------------------------
// attn: 128 rows x 1024-j per 1024-thread block; JTILE=128 (8 fat tiles,
// half the barriers of R5). LDS: wht 64KB + p 32KB = 96KB, 1 block/CU,
// 16 waves. Swizzle: 16 chunks/row, chunk ^= row&15 (2-way aliasing, free).
// grid (32, NSPLIT, 2). Wave w: ih=w>>2 (32 rows), nq=w&3 (64 n-cols).
// ---------------------------------------------------------------------------
__global__ __launch_bounds__(1024, 4) void attn_kernel(
    const int* __restrict__ adj_n, const int* __restrict__ adj_d,
    const u16* __restrict__ WhT,
    const float* __restrict__ s1, const float* __restrict__ s2,
    float* __restrict__ num_ws, float* __restrict__ den_ws)
{
    __shared__ u16 wht_lds[256 * 128];  // 64 KB, swizzled 16B chunks
    __shared__ u16 p_lds[128 * 128];    // 32 KB, swizzled

    const int t = threadIdx.x, lane = t & 63, w = t >> 6;   // w 0..15
    const int q = lane >> 4, ln = lane & 15;
    const int ih = w >> 2;              // i-quarter (32 rows)
    const int nq = w & 3;               // n-quarter (64 cols)
    const int b = blockIdx.z, split = blockIdx.y;
    const int i0 = blockIdx.x * ITILE;

    const int* adjb = b ? adj_d : adj_n;
    const u16* whtB = WhT + ((size_t)b << 20);
    const float* s1b = s1 + b * N_NODES;
    const float* s2b = s2 + b * N_NODES;

    const int pr = t >> 3;              // P row 0..127 (one row per thread)
    const int cw = t & 7;               // j-sixteenth 0..7 (16 j per thread)
    const int pc = cw * 16;
    const float s1v = s1b[i0 + pr];
    const size_t arow = (size_t)(i0 + pr) * N_NODES + pc;

    float den0 = 0.f;                   // full sum lives on (t&7)==0 threads

    f32x4 acc[2][4];
    #pragma unroll
    for (int mt = 0; mt < 2; ++mt)
        #pragma unroll
        for (int nt = 0; nt < 4; ++nt) acc[mt][nt] = (f32x4){0.f, 0.f, 0.f, 0.f};

    const int jbase = split * (N_NODES / NSPLIT);

    int4 a0_pf = *(const int4*)&adjb[arow + jbase];
    int4 a1_pf = *(const int4*)&adjb[arow + jbase + 4];
    int4 a2_pf = *(const int4*)&adjb[arow + jbase + 8];
    int4 a3_pf = *(const int4*)&adjb[arow + jbase + 12];
    float4 s0_pf = *(const float4*)&s2b[jbase + pc];
    float4 s1_pf = *(const float4*)&s2b[jbase + pc + 4];
    float4 s2_pf = *(const float4*)&s2b[jbase + pc + 8];
    float4 s3_pf = *(const float4*)&s2b[jbase + pc + 12];

    for (int jt = 0; jt < NTILES; ++jt) {
        const int j0 = jbase + jt * JTILE;
        __syncthreads();                // wht_lds/p_lds free to overwrite
        #pragma unroll
        for (int it = 0; it < 4; ++it) {   // stage 256n x 128j WhT tile
            int chunk = it * 1024 + t;
            int n = chunk >> 4, kc = chunk & 15;
            const u16* g = whtB + (size_t)n * N_NODES + j0 + ((kc ^ (n & 15)) * 8);
            u16* l = wht_lds + (it * 1024 + w * 64) * 8;
            __builtin_amdgcn_global_load_lds(
                (const __attribute__((address_space(1))) void*)g,
                (__attribute__((address_space(3))) void*)l, 16, 0, 0);
        }
        int4 a0 = a0_pf, a1 = a1_pf, a2 = a2_pf, a3 = a3_pf;
        float4 v0 = s0_pf, v1 = s1_pf, v2 = s2_pf, v3 = s3_pf;
        if (jt < NTILES - 1) {             // prefetch next tile's adj/s2
            const int jn = j0 + JTILE;
            a0_pf = *(const int4*)&adjb[arow + jn];
            a1_pf = *(const int4*)&adjb[arow + jn + 4];
            a2_pf = *(const int4*)&adjb[arow + jn + 8];
            a3_pf = *(const int4*)&adjb[arow + jn + 12];
            s0_pf = *(const float4*)&s2b[jn + pc];
            s1_pf = *(const float4*)&s2b[jn + pc + 4];
            s2_pf = *(const float4*)&s2b[jn + pc + 8];
            s3_pf = *(const float4*)&s2b[jn + pc + 12];
        }
        int   va[16] = {a0.x,a0.y,a0.z,a0.w, a1.x,a1.y,a1.z,a1.w,
                        a2.x,a2.y,a2.z,a2.w, a3.x,a3.y,a3.z,a3.w};
        float vs[16] = {v0.x,v0.y,v0.z,v0.w, v1.x,v1.y,v1.z,v1.w,
                        v2.x,v2.y,v2.z,v2.w, v3.x,v3.y,v3.z,v3.w};
        float d = 0.f;
        u16x8 pk0, pk1;
        #pragma unroll
        for (int jj = 0; jj < 8; ++jj) {
            float x = s1v + vs[jj];
            float p = (va[jj] > 0) ? __expf(fmaxf(x, 0.2f * x)) : 0.f;
            d += p;
            pk0[jj] = f2b_fast(p);
        }
        #pragma unroll
        for (int jj = 0; jj < 8; ++jj) {
            float x = s1v + vs[8 + jj];
            float p = (va[8 + jj] > 0) ? __expf(fmaxf(x, 0.2f * x)) : 0.f;
            d += p;
            pk1[jj] = f2b_fast(p);
        }
        d += __shfl_down(d, 4, 8);
        d += __shfl_down(d, 2, 8);
        d += __shfl_down(d, 1, 8);
        if ((t & 7) == 0) den0 += d;
        *(u16x8*)&p_lds[pr * 128 + (((2 * cw)     ^ (pr & 15)) * 8)] = pk0;
        *(u16x8*)&p_lds[pr * 128 + (((2 * cw + 1) ^ (pr & 15)) * 8)] = pk1;
        __syncthreads();                // staging done + p_lds committed
        #pragma unroll
        for (int ks = 0; ks < 4; ++ks) {
            const int sw = ((ks * 4 + q) ^ ln) * 8;   // row&15 == ln for all rows used
            bf16x8s af0 = *(const bf16x8s*)&p_lds[(ih * 32 + 0 * 16 + ln) * 128 + sw];
            bf16x8s af1 = *(const bf16x8s*)&p_lds[(ih * 32 + 1 * 16 + ln) * 128 + sw];
            #pragma unroll
            for (int nt = 0; nt < 4; ++nt) {
                bf16x8s bfv = *(const bf16x8s*)&wht_lds[(nq * 64 + nt * 16 + ln) * 128 + sw];
                acc[0][nt] = __builtin_amdgcn_mfma_f32_16x16x32_bf16(af0, bfv, acc[0][nt], 0, 0, 0);
                acc[1][nt] = __builtin_amdgcn_mfma_f32_16x16x32_bf16(af1, bfv, acc[1][nt], 0, 0, 0);
            }
        }
    }
    const size_t pbase = (size_t)(b * NSPLIT + split) * N_NODES;
    #pragma unroll
    for (int mt = 0; mt < 2; ++mt)
        #pragma unroll
        for (int r = 0; r < 4; ++r) {
            int row = ih * 32 + mt * 16 + q * 4 + r;
            #pragma unroll
            for (int nt = 0; nt < 4; ++nt)
                num_ws[(pbase + i0 + row) * FOUT + nq * 64 + nt * 16 + ln] = acc[mt][nt][r];
        }
    if ((t & 7) == 0) den_ws[pbase + i0 + pr] = den0;
}

// ---------------------------------------------------------------------------
// reduce: sum splits, elu(num/den), merge branches.
// ---------------------------------------------------------------------------
__global__ __launch_bounds__(256) void reduce_kernel(
    const float* __restrict__ num_ws, const float* __restrict__ den_ws,
    float* __restrict__ out)
{
    int gid = blockIdx.x * 256 + threadIdx.x;
    int i = gid >> 6;
    int f4 = (gid & 63) * 4;
    float4 o = {0.f, 0.f, 0.f, 0.f};
    #pragma unroll
    for (int b = 0; b < 2; ++b) {
        float4 num = {0.f, 0.f, 0.f, 0.f};
        float den = 0.f;
        #pragma unroll
        for (int s = 0; s < NSPLIT; ++s) {
            const float4 v = *(const float4*)&num_ws[((size_t)(b * NSPLIT + s) * N_NODES + i) * FOUT + f4];
            num.x += v.x; num.y += v.y; num.z += v.z; num.w += v.w;
            den += den_ws[(size_t)(b * NSPLIT + s) * N_NODES + i];
        }
        float inv = 1.0f / den;
        float e0 = num.x * inv, e1 = num.y * inv, e2 = num.z * inv, e3 = num.w * inv;
        o.x += (e0 > 0.f) ? e0 : expm1f(e0);
        o.y += (e1 > 0.f) ? e1 : expm1f(e1);
        o.z += (e2 > 0.f) ? e2 : expm1f(e2);
        o.w += (e3 > 0.f) ? e3 : expm1f(e3);
    }
    *(float4*)&out[(size_t)i * FOUT + f4] = o;
}

extern "C" void kernel_launch(void* const* d_in, const int* in_sizes, int n_in,
                              void* d_out, int out_size, void* d_ws, size_t ws_size,
                              hipStream_t stream) {
    const float* h    = (const float*)d_in[0];
    const int*   adjn = (const int*)d_in[1];
    const int*   adjd = (const int*)d_in[2];
    const float* Wn   = (const float*)d_in[4];
    const float* a1n  = (const float*)d_in[5];
    const float* a2n  = (const float*)d_in[6];
    const float* Wd   = (const float*)d_in[7];
    const float* a1d  = (const float*)d_in[8];
    const float* a2d  = (const float*)d_in[9];

    char* ws = (char*)d_ws;
    // [0,4M): WhT   [4M,8M): (free)   [8M,8M+192K): s1,s2,den
    // [8.25M,12.25M): hb   [12.25M,12.75M): WTb   (dead after wh_gemm)
    // [8.25M,40.25M): num  (overlays hb/WTb; written by attn after wh_gemm)
    u16*  WhT  = (u16*)ws;
    float* s1  = (float*)(ws + ((size_t)8 << 20));
    float* s2  = s1 + 2 * N_NODES;
    float* den = s2 + 2 * N_NODES;
    u16*  hb   = (u16*)(ws + ((size_t)8 << 20) + ((size_t)256 << 10));
    u16*  WTb  = (u16*)(ws + ((size_t)12 << 20) + ((size_t)256 << 10));
    float* num = (float*)(ws + ((size_t)8 << 20) + ((size_t)256 << 10));

    prep_kernel<<<1089, 256, 0, stream>>>(h, Wn, Wd, hb, WTb, s1);
    wh_gemm_kernel<<<dim3(64, 4, 2), 256, 0, stream>>>(hb, WTb, a1n, a2n, a1d, a2d, WhT, s1, s2);
    attn_kernel<<<dim3(N_NODES / ITILE, NSPLIT, 2), 1024, 0, stream>>>(adjn, adjd, WhT, s1, s2, num, den);
    reduce_kernel<<<1024, 256, 0, stream>>>(num, den, (float*)d_out);
}